// Round 10
// baseline (294.479 us; speedup 1.0000x reference)
//
#include <hip/hip_runtime.h>

#define B_    4
#define S_    2048
#define H_    8
#define M_    (B_ * S_)   // 8192

typedef __bf16    bf16_t;
typedef _Float16  f16_t;
typedef __bf16   bf16x8 __attribute__((ext_vector_type(8)));
typedef __bf16   bf16x4 __attribute__((ext_vector_type(4)));
typedef _Float16 f16x8  __attribute__((ext_vector_type(8)));
typedef float    f32x16 __attribute__((ext_vector_type(16)));

union B8 { uint4 u; bf16x8 v; bf16_t e[8]; };
union B4 { uint2 u; bf16x4 v; bf16_t e[4]; };
union H8 { uint4 u; f16x8  v; f16_t  e[8]; };
union H4 { uint2 u; f16_t  e[4]; };

#define QSCALE 0.1803368801111204f   // 0.125 * log2(e): scores exit in log2 domain

// ---------------------------------------------------------------------------
// All weight converts in ONE launch. grid (8, 8, 4), 256 thr.
// z<3:  W[z] [8,512,64] fp32 -> Wt[z] [8,64,512] bf16 (y = head, x = k-tile)
// z==3: Wo [512,512] fp32 -> Wot [512n][512k] f16    (y = n-tile, x = k-tile)
// ---------------------------------------------------------------------------
__global__ __launch_bounds__(256) void convert_weights(
    const float* __restrict__ w0, const float* __restrict__ w1,
    const float* __restrict__ w2, const float* __restrict__ wo,
    bf16_t* __restrict__ t0, bf16_t* __restrict__ t1,
    bf16_t* __restrict__ t2, f16_t* __restrict__ wot)
{
    __shared__ float T[64][65];
    const int z   = blockIdx.z;
    const int k0  = blockIdx.x * 64;
    const int tid = threadIdx.x;
    const int row = tid & 63, q4 = tid >> 6;

    if (z < 3) {
        const float* W  = z == 0 ? w0 : z == 1 ? w1 : w2;
        bf16_t*      Wt = z == 0 ? t0 : z == 1 ? t1 : t2;
        const int h = blockIdx.y;
        const float* Wh = W + (size_t)h * 512 * 64;
        #pragma unroll
        for (int i = 0; i < 4; ++i) {
            int fq = q4 * 4 + i;
            float4 v = *(const float4*)(Wh + (size_t)(k0 + row) * 64 + fq * 4);
            T[row][fq * 4 + 0] = v.x; T[row][fq * 4 + 1] = v.y;
            T[row][fq * 4 + 2] = v.z; T[row][fq * 4 + 3] = v.w;
        }
        __syncthreads();
        bf16_t* Wth = Wt + (size_t)h * 64 * 512;
        #pragma unroll
        for (int i = 0; i < 4; ++i) {
            int kq = q4 * 4 + i;
            B4 o;
            #pragma unroll
            for (int j = 0; j < 4; ++j) o.e[j] = (bf16_t)T[kq * 4 + j][row];
            *(uint2*)(Wth + (size_t)row * 512 + k0 + kq * 4) = o.u;
        }
    } else {
        const int n0 = blockIdx.y * 64;
        #pragma unroll
        for (int i = 0; i < 4; ++i) {
            int fq = q4 * 4 + i;
            float4 v = *(const float4*)(wo + (size_t)(k0 + row) * 512 + n0 + fq * 4);
            T[row][fq * 4 + 0] = v.x; T[row][fq * 4 + 1] = v.y;
            T[row][fq * 4 + 2] = v.z; T[row][fq * 4 + 3] = v.w;
        }
        __syncthreads();
        #pragma unroll
        for (int i = 0; i < 4; ++i) {
            int kq = q4 * 4 + i;
            H4 o;
            #pragma unroll
            for (int j = 0; j < 4; ++j) o.e[j] = (f16_t)T[kq * 4 + j][row];
            *(uint2*)(wot + (size_t)(n0 + row) * 512 + k0 + kq * 4) = o.u;
        }
    }
}

// ---------------------------------------------------------------------------
// LDS-tiled QKV projection: 64M x 128N x BK=64, 4 waves (2x2 of 32Mx64N).
// grid (128 m-tiles, 4 n-tiles, 3 matrices) = 1536 blocks (~5 blocks/CU).
// Register double-buffer prefetch. A staged fp32->bf16 in-flight.
// z==0: Q -> concat bf16 scaled QSCALE; z==1: K; z==2: V -> Vt (transposed).
// C/D: col(n)=lane&31, row(m)=(r&3)+8*(r>>2)+4*half.
// ---------------------------------------------------------------------------
__global__ __launch_bounds__(256) void proj_tiled(
    const float* __restrict__ xq, const float* __restrict__ xk,
    const float* __restrict__ xv,
    const bf16_t* __restrict__ Wtq, const bf16_t* __restrict__ Wtk,
    const bf16_t* __restrict__ Wtv,
    const float* __restrict__ bq, const float* __restrict__ bk,
    const float* __restrict__ bv,
    bf16_t* __restrict__ Qb, bf16_t* __restrict__ Kb, bf16_t* __restrict__ Vt)
{
    __shared__ bf16_t As[64 * 72];
    __shared__ bf16_t Bs[128 * 72];

    const int z = blockIdx.z;
    const float*  X    = z == 0 ? xq  : z == 1 ? xk  : xv;
    const bf16_t* Wt   = z == 0 ? Wtq : z == 1 ? Wtk : Wtv;
    const float*  bias = z == 0 ? bq  : z == 1 ? bk  : bv;

    const int tid  = threadIdx.x;
    const int wave = tid >> 6, lane = tid & 63;
    const int l31  = lane & 31, half = lane >> 5;
    const int m0   = blockIdx.x * 64;
    const int n0   = blockIdx.y * 128;
    const int mw   = (wave & 1) * 32;
    const int nw   = (wave >> 1) * 64;

    const int sra = tid >> 2, sca = (tid & 3) * 16;   // A: 64 rows x 16 cols
    const int srb = tid >> 1, scb = (tid & 1) * 32;   // B: 128 rows x 32 cols

    float4 ra[4];
    uint4  rb[4];
    {
        const float*  ap = X  + (size_t)(m0 + sra) * 512 + sca;
        const bf16_t* bp = Wt + (size_t)(n0 + srb) * 512 + scb;
        #pragma unroll
        for (int i = 0; i < 4; ++i) {
            ra[i] = *(const float4*)(ap + i * 4);
            rb[i] = *(const uint4*)(bp + i * 8);
        }
    }

    f32x16 acc0, acc1;
    #pragma unroll
    for (int i = 0; i < 16; ++i) { acc0[i] = 0.0f; acc1[i] = 0.0f; }

    for (int k0 = 0; k0 < 512; k0 += 64) {
        __syncthreads();
        {
            B8 w0, w1;
            w0.e[0] = (bf16_t)ra[0].x; w0.e[1] = (bf16_t)ra[0].y;
            w0.e[2] = (bf16_t)ra[0].z; w0.e[3] = (bf16_t)ra[0].w;
            w0.e[4] = (bf16_t)ra[1].x; w0.e[5] = (bf16_t)ra[1].y;
            w0.e[6] = (bf16_t)ra[1].z; w0.e[7] = (bf16_t)ra[1].w;
            w1.e[0] = (bf16_t)ra[2].x; w1.e[1] = (bf16_t)ra[2].y;
            w1.e[2] = (bf16_t)ra[2].z; w1.e[3] = (bf16_t)ra[2].w;
            w1.e[4] = (bf16_t)ra[3].x; w1.e[5] = (bf16_t)ra[3].y;
            w1.e[6] = (bf16_t)ra[3].z; w1.e[7] = (bf16_t)ra[3].w;
            *(uint4*)&As[sra * 72 + sca]     = w0.u;
            *(uint4*)&As[sra * 72 + sca + 8] = w1.u;
            #pragma unroll
            for (int i = 0; i < 4; ++i)
                *(uint4*)&Bs[srb * 72 + scb + i * 8] = rb[i];
        }
        if (k0 + 64 < 512) {
            const float*  ap = X  + (size_t)(m0 + sra) * 512 + k0 + 64 + sca;
            const bf16_t* bp = Wt + (size_t)(n0 + srb) * 512 + k0 + 64 + scb;
            #pragma unroll
            for (int i = 0; i < 4; ++i) {
                ra[i] = *(const float4*)(ap + i * 4);
                rb[i] = *(const uint4*)(bp + i * 8);
            }
        }
        __syncthreads();

        #pragma unroll
        for (int kc = 0; kc < 4; ++kc) {
            B8 a, b0, b1;
            a.u  = *(const uint4*)&As[(mw + l31)      * 72 + kc * 16 + half * 8];
            b0.u = *(const uint4*)&Bs[(nw + l31)      * 72 + kc * 16 + half * 8];
            b1.u = *(const uint4*)&Bs[(nw + 32 + l31) * 72 + kc * 16 + half * 8];
            acc0 = __builtin_amdgcn_mfma_f32_32x32x16_bf16(a.v, b0.v, acc0, 0, 0, 0);
            acc1 = __builtin_amdgcn_mfma_f32_32x32x16_bf16(a.v, b1.v, acc1, 0, 0, 0);
        }
    }

    if (z <= 1) {
        const float sc_ = (z == 0) ? QSCALE : 1.0f;
        bf16_t* Out = (z == 0) ? Qb : Kb;
        #pragma unroll
        for (int nt = 0; nt < 2; ++nt) {
            int n = n0 + nw + nt * 32 + l31;
            float bv_ = bias[n];
            const f32x16& ac = nt ? acc1 : acc0;
            #pragma unroll
            for (int r = 0; r < 16; ++r) {
                int m = m0 + mw + (r & 3) + 8 * (r >> 2) + 4 * half;
                Out[(size_t)m * 512 + n] = (bf16_t)((ac[r] + bv_) * sc_);
            }
        }
    } else {
        const int b  = m0 >> 11;
        const int sb = (m0 & 2047) + mw;
        #pragma unroll
        for (int nt = 0; nt < 2; ++nt) {
            int n = n0 + nw + nt * 32 + l31;
            float bv_ = bias[n];
            int h = n >> 6, d = n & 63;
            const f32x16& ac = nt ? acc1 : acc0;
            bf16_t* base = Vt + ((size_t)(b * 8 + h) * 64 + d) * 2048 + sb;
            #pragma unroll
            for (int g = 0; g < 4; ++g) {
                B4 p;
                #pragma unroll
                for (int j = 0; j < 4; ++j) p.e[j] = (bf16_t)(ac[g * 4 + j] + bv_);
                *(uint2*)(base + 8 * g + 4 * half) = p.u;
            }
        }
    }
}

// ---------------------------------------------------------------------------
// MFMA flash attention, q-tile 64, 256 thr (4 waves), in-block 2-way key
// split: waves {0,1} keys [0,1024) (qsub=wave&1), waves {2,3} keys
// [1024,2048). Unnormalized partials combine linearly via LDS (no-max
// softmax in log2 domain). grid (S/64, B*H) = 1024 blocks -> 4 blocks/CU.
// Q pre-scaled by 0.125*log2e in projection.
// ---------------------------------------------------------------------------
__global__ __launch_bounds__(256) void attn_mfma(
    const bf16_t* __restrict__ Q, const bf16_t* __restrict__ K,
    const bf16_t* __restrict__ Vt, f16_t* __restrict__ O)
{
    __shared__ char smraw[36864];
    bf16_t* KsBuf = (bf16_t*)smraw;            // [2][64*72]
    bf16_t* VsBuf = KsBuf + 2 * 64 * 72;       // [2][64*72]

    const int bh  = blockIdx.y;
    const int b   = bh >> 3, h = bh & 7;
    const int q0  = blockIdx.x * 64;
    const int tid = threadIdx.x;
    const int wave = tid >> 6, lane = tid & 63;
    const int l31 = lane & 31, half = lane >> 5;
    const int qsub = wave & 1, ksplit = wave >> 1;

    // Q fragments (B-operand: n=query=l31, k=d)
    bf16x8 qf[4];
    {
        const bf16_t* qp = Q + ((size_t)(b * S_ + q0 + qsub * 32 + l31)) * 512 + h * 64 + half * 8;
        #pragma unroll
        for (int ks = 0; ks < 4; ++ks) {
            B8 t; t.u = *(const uint4*)(qp + ks * 16);
            qf[ks] = t.v;
        }
    }

    f32x16 o0, o1;
    #pragma unroll
    for (int i = 0; i < 16; ++i) { o0[i] = 0.0f; o1[i] = 0.0f; }
    float l_i = 0.0f;

    const bf16_t* Kbase = K + ((size_t)b * S_) * 512 + h * 64;
    const bf16_t* Vbase = Vt + ((size_t)bh * 64) * 2048;

    // staging: threads 0-127 fill buffer 0, 128-255 buffer 1
    const int sbuf = tid >> 7;
    const int p    = tid & 127;
    const int kqmap[4] = {0, 2, 1, 3};
    const int vj  = p & 3;
    const int vkq = kqmap[vj];
    bf16_t* KsS = KsBuf + sbuf * (64 * 72);
    bf16_t* VsS = VsBuf + sbuf * (64 * 72);
    const bf16_t* KsC = KsBuf + ksplit * (64 * 72);
    const bf16_t* VsC = VsBuf + ksplit * (64 * 72);

    for (int t0 = 0; t0 < 1024; t0 += 64) {
        const int tb = sbuf * 1024 + t0;
        __syncthreads();
        #pragma unroll
        for (int l = 0; l < 4; ++l) {
            int idx = p + l * 128;
            int row = idx >> 3, c8 = idx & 7;
            *(uint4*)&KsS[row * 72 + c8 * 8] =
                *(const uint4*)(Kbase + (size_t)(tb + row) * 512 + c8 * 8);
        }
        #pragma unroll
        for (int l = 0; l < 2; ++l) {
            int vd = (p >> 2) + 32 * l;
            #pragma unroll
            for (int g = 0; g < 4; ++g)
                *(uint2*)&VsS[vd * 72 + g * 16 + vj * 4] =
                    *(const uint2*)(Vbase + (size_t)vd * 2048 + tb + g * 16 + vkq * 4);
        }
        __syncthreads();

        // ---- S^T = K Q^T : lane holds 32 scores (log2 domain) of query l31
        f32x16 s0, s1;
        #pragma unroll
        for (int i = 0; i < 16; ++i) { s0[i] = 0.0f; s1[i] = 0.0f; }
        #pragma unroll
        for (int ks = 0; ks < 4; ++ks) {
            B8 k0, k1;
            k0.u = *(const uint4*)(&KsC[l31 * 72 + ks * 16 + half * 8]);
            k1.u = *(const uint4*)(&KsC[(32 + l31) * 72 + ks * 16 + half * 8]);
            s0 = __builtin_amdgcn_mfma_f32_32x32x16_bf16(k0.v, qf[ks], s0, 0, 0, 0);
            s1 = __builtin_amdgcn_mfma_f32_32x32x16_bf16(k1.v, qf[ks], s1, 0, 0, 0);
        }

        // ---- p = 2^s (bare v_exp_f32), accumulate l, pack P^T frags ----
        float ls = 0.0f;
        #pragma unroll
        for (int r = 0; r < 16; ++r) {
            s0[r] = __builtin_amdgcn_exp2f(s0[r]); ls += s0[r];
            s1[r] = __builtin_amdgcn_exp2f(s1[r]); ls += s1[r];
        }
        l_i += ls;

        B8 pf[4];
        #pragma unroll
        for (int j = 0; j < 8; ++j) {
            pf[0].e[j] = (bf16_t)s0[j];
            pf[1].e[j] = (bf16_t)s0[8 + j];
            pf[2].e[j] = (bf16_t)s1[j];
            pf[3].e[j] = (bf16_t)s1[8 + j];
        }

        // ---- O^T += V^T P^T ----
        #pragma unroll
        for (int c = 0; c < 4; ++c) {
            B8 va, vb;
            va.u = *(const uint4*)(&VsC[l31 * 72 + c * 16 + half * 8]);
            vb.u = *(const uint4*)(&VsC[(32 + l31) * 72 + c * 16 + half * 8]);
            o0 = __builtin_amdgcn_mfma_f32_32x32x16_bf16(va.v, pf[c].v, o0, 0, 0, 0);
            o1 = __builtin_amdgcn_mfma_f32_32x32x16_bf16(vb.v, pf[c].v, o1, 0, 0, 0);
        }
    }

    // ---- combine key-split partials via LDS, then normalize + store ----
    l_i += __shfl_xor(l_i, 32);
    __syncthreads();
    float* co = (float*)smraw;                 // [2][32*68]
    float* cl = co + 2 * 32 * 68;              // [2][64]
    if (ksplit == 1) {
        float* reg = co + qsub * (32 * 68);
        #pragma unroll
        for (int r = 0; r < 16; ++r) {
            reg[r * 68 + lane]        = o0[r];
            reg[(16 + r) * 68 + lane] = o1[r];
        }
        cl[qsub * 64 + lane] = l_i;
    }
    __syncthreads();
    if (ksplit == 0) {
        float* reg = co + qsub * (32 * 68);
        float inv = 1.0f / (l_i + cl[qsub * 64 + lane]);
        f16_t* Ob = O + ((size_t)(b * S_ + q0 + qsub * 32 + l31)) * 512 + h * 64;
        #pragma unroll
        for (int g = 0; g < 4; ++g) {
            H4 a, c;
            #pragma unroll
            for (int j = 0; j < 4; ++j) {
                int r = g * 4 + j;
                a.e[j] = (f16_t)((o0[r] + reg[r * 68 + lane]) * inv);
                c.e[j] = (f16_t)((o1[r] + reg[(16 + r) * 68 + lane]) * inv);
            }
            int d = 8 * g + 4 * half;
            *(uint2*)(Ob + d)      = a.u;
            *(uint2*)(Ob + 32 + d) = c.u;
        }
    }
}

// ---------------------------------------------------------------------------
// LDS-tiled output GEMM with register prefetch: 64x64x64, 4 waves (2x2 of
// 32x32). out = AO(f16) @ Wot^T + bo, fp32 out. grid (128, 8), 256 thr.
// ---------------------------------------------------------------------------
__global__ __launch_bounds__(256) void gemm_out_tiled(
    const f16_t* __restrict__ A, const f16_t* __restrict__ Wot,
    const float* __restrict__ bias, float* __restrict__ C)
{
    __shared__ f16_t As[64 * 72];
    __shared__ f16_t Bs[64 * 72];

    const int tid  = threadIdx.x;
    const int wave = tid >> 6, lane = tid & 63;
    const int l31  = lane & 31, half = lane >> 5;
    const int m0   = blockIdx.x * 64;
    const int n0   = blockIdx.y * 64;
    const int mw   = (wave & 1) * 32;
    const int nw   = (wave >> 1) * 32;

    const int sr  = tid >> 2;           // staging row 0..63
    const int so  = (tid & 3) * 16;     // staging col 0/16/32/48

    uint4 pA0, pA1, pB0, pB1;
    {
        const f16_t* ap = A   + (size_t)(m0 + sr) * 512 + so;
        const f16_t* bp = Wot + (size_t)(n0 + sr) * 512 + so;
        pA0 = *(const uint4*)(ap); pA1 = *(const uint4*)(ap + 8);
        pB0 = *(const uint4*)(bp); pB1 = *(const uint4*)(bp + 8);
    }

    f32x16 acc;
    #pragma unroll
    for (int i = 0; i < 16; ++i) acc[i] = 0.0f;

    for (int k0 = 0; k0 < 512; k0 += 64) {
        __syncthreads();
        *(uint4*)&As[sr * 72 + so]     = pA0;
        *(uint4*)&As[sr * 72 + so + 8] = pA1;
        *(uint4*)&Bs[sr * 72 + so]     = pB0;
        *(uint4*)&Bs[sr * 72 + so + 8] = pB1;
        if (k0 + 64 < 512) {
            const f16_t* ap = A   + (size_t)(m0 + sr) * 512 + k0 + 64 + so;
            const f16_t* bp = Wot + (size_t)(n0 + sr) * 512 + k0 + 64 + so;
            pA0 = *(const uint4*)(ap); pA1 = *(const uint4*)(ap + 8);
            pB0 = *(const uint4*)(bp); pB1 = *(const uint4*)(bp + 8);
        }
        __syncthreads();

        #pragma unroll
        for (int kc = 0; kc < 4; ++kc) {
            H8 a, b;
            a.u = *(const uint4*)&As[(mw + l31) * 72 + kc * 16 + half * 8];
            b.u = *(const uint4*)&Bs[(nw + l31) * 72 + kc * 16 + half * 8];
            acc = __builtin_amdgcn_mfma_f32_32x32x16_f16(a.v, b.v, acc, 0, 0, 0);
        }
    }

    const int n = n0 + nw + l31;
    const float bias0 = bias[n];
    #pragma unroll
    for (int r = 0; r < 16; ++r) {
        int m = m0 + mw + (r & 3) + 8 * (r >> 2) + 4 * half;
        C[(size_t)m * 512 + n] = acc[r] + bias0;
    }
}

// ---------------------------------------------------------------------------
extern "C" void kernel_launch(void* const* d_in, const int* in_sizes, int n_in,
                              void* d_out, int out_size, void* d_ws, size_t ws_size,
                              hipStream_t stream)
{
    const float* x_q = (const float*)d_in[0];
    const float* x_k = (const float*)d_in[1];
    const float* x_v = (const float*)d_in[2];
    const float* Wq  = (const float*)d_in[3];
    const float* bq  = (const float*)d_in[4];
    const float* Wk  = (const float*)d_in[5];
    const float* bk  = (const float*)d_in[6];
    const float* Wv  = (const float*)d_in[7];
    const float* bv  = (const float*)d_in[8];
    const float* Wo  = (const float*)d_in[9];
    const float* bo  = (const float*)d_in[10];
    float* out = (float*)d_out;

    // ws layout (~34 MB)
    char* W = (char*)d_ws;
    bf16_t* Wtq = (bf16_t*)W;                                    // 512 KB
    bf16_t* Wtk = Wtq + (size_t)8 * 64 * 512;
    bf16_t* Wtv = Wtk + (size_t)8 * 64 * 512;
    f16_t*  Wot = (f16_t*)(Wtv + (size_t)8 * 64 * 512);          // 512 KB
    bf16_t* Qb  = (bf16_t*)(Wot + (size_t)512 * 512);            // 8 MB
    bf16_t* Kb  = Qb + (size_t)M_ * 512;                         // 8 MB
    bf16_t* Vt  = Kb + (size_t)M_ * 512;                         // 8 MB
    f16_t*  AO  = (f16_t*)(Vt + (size_t)M_ * 512);               // 8 MB

    convert_weights<<<dim3(8, 8, 4), 256, 0, stream>>>(
        Wq, Wk, Wv, Wo, Wtq, Wtk, Wtv, Wot);

    proj_tiled<<<dim3(128, 4, 3), 256, 0, stream>>>(
        x_q, x_k, x_v, Wtq, Wtk, Wtv, bq, bk, bv, Qb, Kb, Vt);

    attn_mfma<<<dim3(S_ / 64, B_ * H_), 256, 0, stream>>>(Qb, Kb, Vt, AO);

    gemm_out_tiled<<<dim3(128, 8), 256, 0, stream>>>(AO, Wot, bo, out);
}

// Round 11
// 235.768 us; speedup vs baseline: 1.2490x; 1.2490x over previous
//
#include <hip/hip_runtime.h>

#define B_    4
#define S_    2048
#define H_    8
#define M_    (B_ * S_)   // 8192

typedef __bf16    bf16_t;
typedef _Float16  f16_t;
typedef __bf16   bf16x8 __attribute__((ext_vector_type(8)));
typedef __bf16   bf16x4 __attribute__((ext_vector_type(4)));
typedef _Float16 f16x8  __attribute__((ext_vector_type(8)));
typedef float    f32x16 __attribute__((ext_vector_type(16)));

union B8 { uint4 u; bf16x8 v; bf16_t e[8]; };
union B4 { uint2 u; bf16x4 v; bf16_t e[4]; };
union H8 { uint4 u; f16x8  v; f16_t  e[8]; };
union H4 { uint2 u; f16_t  e[4]; };

#define QSCALE 0.1803368801111204f   // 0.125 * log2(e): scores exit in log2 domain

// ---------------------------------------------------------------------------
// All weight converts in ONE launch. grid (8, 8, 4), 256 thr.
// z<3:  W[z] [8,512,64] fp32 -> Wt[z] [8,64,512] bf16 (y = head, x = k-tile)
// z==3: Wo [512,512] fp32 -> Wot [512n][512k] f16    (y = n-tile, x = k-tile)
// ---------------------------------------------------------------------------
__global__ __launch_bounds__(256) void convert_weights(
    const float* __restrict__ w0, const float* __restrict__ w1,
    const float* __restrict__ w2, const float* __restrict__ wo,
    bf16_t* __restrict__ t0, bf16_t* __restrict__ t1,
    bf16_t* __restrict__ t2, f16_t* __restrict__ wot)
{
    __shared__ float T[64][65];
    const int z   = blockIdx.z;
    const int k0  = blockIdx.x * 64;
    const int tid = threadIdx.x;
    const int row = tid & 63, q4 = tid >> 6;

    if (z < 3) {
        const float* W  = z == 0 ? w0 : z == 1 ? w1 : w2;
        bf16_t*      Wt = z == 0 ? t0 : z == 1 ? t1 : t2;
        const int h = blockIdx.y;
        const float* Wh = W + (size_t)h * 512 * 64;
        #pragma unroll
        for (int i = 0; i < 4; ++i) {
            int fq = q4 * 4 + i;
            float4 v = *(const float4*)(Wh + (size_t)(k0 + row) * 64 + fq * 4);
            T[row][fq * 4 + 0] = v.x; T[row][fq * 4 + 1] = v.y;
            T[row][fq * 4 + 2] = v.z; T[row][fq * 4 + 3] = v.w;
        }
        __syncthreads();
        bf16_t* Wth = Wt + (size_t)h * 64 * 512;
        #pragma unroll
        for (int i = 0; i < 4; ++i) {
            int kq = q4 * 4 + i;
            B4 o;
            #pragma unroll
            for (int j = 0; j < 4; ++j) o.e[j] = (bf16_t)T[kq * 4 + j][row];
            *(uint2*)(Wth + (size_t)row * 512 + k0 + kq * 4) = o.u;
        }
    } else {
        const int n0 = blockIdx.y * 64;
        #pragma unroll
        for (int i = 0; i < 4; ++i) {
            int fq = q4 * 4 + i;
            float4 v = *(const float4*)(wo + (size_t)(k0 + row) * 512 + n0 + fq * 4);
            T[row][fq * 4 + 0] = v.x; T[row][fq * 4 + 1] = v.y;
            T[row][fq * 4 + 2] = v.z; T[row][fq * 4 + 3] = v.w;
        }
        __syncthreads();
        #pragma unroll
        for (int i = 0; i < 4; ++i) {
            int kq = q4 * 4 + i;
            H4 o;
            #pragma unroll
            for (int j = 0; j < 4; ++j) o.e[j] = (f16_t)T[kq * 4 + j][row];
            *(uint2*)(wot + (size_t)(n0 + row) * 512 + k0 + kq * 4) = o.u;
        }
    }
}

// ---------------------------------------------------------------------------
// LDS-tiled QKV projection: 64M x 128N x BK=64, 4 waves (2x2 of 32Mx64N).
// grid (128, 4, 3). Prefetch issued AFTER the post-staging barrier so the
// compiler's vmcnt(0)-before-barrier drain lands after compute, not before.
// z==0: Q -> concat bf16 scaled QSCALE; z==1: K; z==2: V -> Vt (transposed).
// C/D: col(n)=lane&31, row(m)=(r&3)+8*(r>>2)+4*half.
// ---------------------------------------------------------------------------
__global__ __launch_bounds__(256) void proj_tiled(
    const float* __restrict__ xq, const float* __restrict__ xk,
    const float* __restrict__ xv,
    const bf16_t* __restrict__ Wtq, const bf16_t* __restrict__ Wtk,
    const bf16_t* __restrict__ Wtv,
    const float* __restrict__ bq, const float* __restrict__ bk,
    const float* __restrict__ bv,
    bf16_t* __restrict__ Qb, bf16_t* __restrict__ Kb, bf16_t* __restrict__ Vt)
{
    __shared__ bf16_t As[64 * 72];
    __shared__ bf16_t Bs[128 * 72];

    const int z = blockIdx.z;
    const float*  X    = z == 0 ? xq  : z == 1 ? xk  : xv;
    const bf16_t* Wt   = z == 0 ? Wtq : z == 1 ? Wtk : Wtv;
    const float*  bias = z == 0 ? bq  : z == 1 ? bk  : bv;

    const int tid  = threadIdx.x;
    const int wave = tid >> 6, lane = tid & 63;
    const int l31  = lane & 31, half = lane >> 5;
    const int m0   = blockIdx.x * 64;
    const int n0   = blockIdx.y * 128;
    const int mw   = (wave & 1) * 32;
    const int nw   = (wave >> 1) * 64;

    const int sra = tid >> 2, sca = (tid & 3) * 16;   // A: 64 rows x 16 cols
    const int srb = tid >> 1, scb = (tid & 1) * 32;   // B: 128 rows x 32 cols

    float4 ra[4];
    uint4  rb[4];
    {
        const float*  ap = X  + (size_t)(m0 + sra) * 512 + sca;
        const bf16_t* bp = Wt + (size_t)(n0 + srb) * 512 + scb;
        #pragma unroll
        for (int i = 0; i < 4; ++i) {
            ra[i] = *(const float4*)(ap + i * 4);
            rb[i] = *(const uint4*)(bp + i * 8);
        }
    }

    f32x16 acc0, acc1;
    #pragma unroll
    for (int i = 0; i < 16; ++i) { acc0[i] = 0.0f; acc1[i] = 0.0f; }

    for (int k0 = 0; k0 < 512; k0 += 64) {
        __syncthreads();
        {
            B8 w0, w1;
            w0.e[0] = (bf16_t)ra[0].x; w0.e[1] = (bf16_t)ra[0].y;
            w0.e[2] = (bf16_t)ra[0].z; w0.e[3] = (bf16_t)ra[0].w;
            w0.e[4] = (bf16_t)ra[1].x; w0.e[5] = (bf16_t)ra[1].y;
            w0.e[6] = (bf16_t)ra[1].z; w0.e[7] = (bf16_t)ra[1].w;
            w1.e[0] = (bf16_t)ra[2].x; w1.e[1] = (bf16_t)ra[2].y;
            w1.e[2] = (bf16_t)ra[2].z; w1.e[3] = (bf16_t)ra[2].w;
            w1.e[4] = (bf16_t)ra[3].x; w1.e[5] = (bf16_t)ra[3].y;
            w1.e[6] = (bf16_t)ra[3].z; w1.e[7] = (bf16_t)ra[3].w;
            *(uint4*)&As[sra * 72 + sca]     = w0.u;
            *(uint4*)&As[sra * 72 + sca + 8] = w1.u;
            #pragma unroll
            for (int i = 0; i < 4; ++i)
                *(uint4*)&Bs[srb * 72 + scb + i * 8] = rb[i];
        }
        __syncthreads();
        // prefetch AFTER the barrier: drain happens at next iter's barrier,
        // i.e. after the whole compute phase below.
        if (k0 + 64 < 512) {
            const float*  ap = X  + (size_t)(m0 + sra) * 512 + k0 + 64 + sca;
            const bf16_t* bp = Wt + (size_t)(n0 + srb) * 512 + k0 + 64 + scb;
            #pragma unroll
            for (int i = 0; i < 4; ++i) {
                ra[i] = *(const float4*)(ap + i * 4);
                rb[i] = *(const uint4*)(bp + i * 8);
            }
        }

        #pragma unroll
        for (int kc = 0; kc < 4; ++kc) {
            B8 a, b0, b1;
            a.u  = *(const uint4*)&As[(mw + l31)      * 72 + kc * 16 + half * 8];
            b0.u = *(const uint4*)&Bs[(nw + l31)      * 72 + kc * 16 + half * 8];
            b1.u = *(const uint4*)&Bs[(nw + 32 + l31) * 72 + kc * 16 + half * 8];
            acc0 = __builtin_amdgcn_mfma_f32_32x32x16_bf16(a.v, b0.v, acc0, 0, 0, 0);
            acc1 = __builtin_amdgcn_mfma_f32_32x32x16_bf16(a.v, b1.v, acc1, 0, 0, 0);
        }
    }

    if (z <= 1) {
        const float sc_ = (z == 0) ? QSCALE : 1.0f;
        bf16_t* Out = (z == 0) ? Qb : Kb;
        #pragma unroll
        for (int nt = 0; nt < 2; ++nt) {
            int n = n0 + nw + nt * 32 + l31;
            float bv_ = bias[n];
            const f32x16& ac = nt ? acc1 : acc0;
            #pragma unroll
            for (int r = 0; r < 16; ++r) {
                int m = m0 + mw + (r & 3) + 8 * (r >> 2) + 4 * half;
                Out[(size_t)m * 512 + n] = (bf16_t)((ac[r] + bv_) * sc_);
            }
        }
    } else {
        const int b  = m0 >> 11;
        const int sb = (m0 & 2047) + mw;
        #pragma unroll
        for (int nt = 0; nt < 2; ++nt) {
            int n = n0 + nw + nt * 32 + l31;
            float bv_ = bias[n];
            int h = n >> 6, d = n & 63;
            const f32x16& ac = nt ? acc1 : acc0;
            bf16_t* base = Vt + ((size_t)(b * 8 + h) * 64 + d) * 2048 + sb;
            #pragma unroll
            for (int g = 0; g < 4; ++g) {
                B4 p;
                #pragma unroll
                for (int j = 0; j < 4; ++j) p.e[j] = (bf16_t)(ac[g * 4 + j] + bv_);
                *(uint2*)(base + 8 * g + 4 * half) = p.u;
            }
        }
    }
}

// ---------------------------------------------------------------------------
// MFMA flash attention (R9 512-thr structure + post-barrier reg prefetch).
// Block = 512 thr (8 waves): waves 0-3 keys [0,1024) (qsub=wave&3), waves
// 4-7 keys [1024,2048). Unnormalized partials combine linearly (no-max
// softmax, log2 domain) via one-time LDS exchange. Q-tile 128/block.
// grid (S/128, B*H) = 512 blocks, 16 waves/CU. Q pre-scaled by 0.125*log2e.
// ---------------------------------------------------------------------------
__global__ __launch_bounds__(512) void attn_mfma(
    const bf16_t* __restrict__ Q, const bf16_t* __restrict__ K,
    const bf16_t* __restrict__ Vt, f16_t* __restrict__ O)
{
    __shared__ char smraw[36864];
    bf16_t* KsBuf = (bf16_t*)smraw;            // [2][64*72]
    bf16_t* VsBuf = KsBuf + 2 * 64 * 72;       // [2][64*72]

    const int bh  = blockIdx.y;
    const int b   = bh >> 3, h = bh & 7;
    const int q0  = blockIdx.x * 128;
    const int tid = threadIdx.x;
    const int wave = tid >> 6, lane = tid & 63;
    const int l31 = lane & 31, half = lane >> 5;
    const int qsub = wave & 3, ksplit = wave >> 2;

    // Q fragments (B-operand: n=query=l31, k=d)
    bf16x8 qf[4];
    {
        const bf16_t* qp = Q + ((size_t)(b * S_ + q0 + qsub * 32 + l31)) * 512 + h * 64 + half * 8;
        #pragma unroll
        for (int ks = 0; ks < 4; ++ks) {
            B8 t; t.u = *(const uint4*)(qp + ks * 16);
            qf[ks] = t.v;
        }
    }

    f32x16 o0, o1;
    #pragma unroll
    for (int i = 0; i < 16; ++i) { o0[i] = 0.0f; o1[i] = 0.0f; }
    float l_i = 0.0f;

    const bf16_t* Kbase = K + ((size_t)b * S_) * 512 + h * 64;
    const bf16_t* Vbase = Vt + ((size_t)bh * 64) * 2048;

    // staging: threads 0-255 fill buffer 0 (keys 0-1023), 256-511 buffer 1
    const int sbuf = tid >> 8;
    const int p    = tid & 255;
    const int kr = p >> 3, kc8 = p & 7;
    const int vd = p >> 2, vj = p & 3;
    const int kqmap[4] = {0, 2, 1, 3};
    const int vkq = kqmap[vj];
    bf16_t* KsS = KsBuf + sbuf * (64 * 72);
    bf16_t* VsS = VsBuf + sbuf * (64 * 72);
    const bf16_t* KsC = KsBuf + ksplit * (64 * 72);
    const bf16_t* VsC = VsBuf + ksplit * (64 * 72);

    // register staging (prefetch): 2 uint4 K + 4 uint2 V per thread
    uint4 kreg0, kreg1;
    uint2 vreg[4];
    {
        const int tb = sbuf * 1024;
        kreg0 = *(const uint4*)(Kbase + (size_t)(tb + kr) * 512 + kc8 * 8);
        kreg1 = *(const uint4*)(Kbase + (size_t)(tb + kr + 32) * 512 + kc8 * 8);
        #pragma unroll
        for (int g = 0; g < 4; ++g)
            vreg[g] = *(const uint2*)(Vbase + (size_t)vd * 2048 + tb + g * 16 + vkq * 4);
    }

    for (int t0 = 0; t0 < 1024; t0 += 64) {
        __syncthreads();
        *(uint4*)&KsS[kr * 72 + kc8 * 8]        = kreg0;
        *(uint4*)&KsS[(kr + 32) * 72 + kc8 * 8] = kreg1;
        #pragma unroll
        for (int g = 0; g < 4; ++g)
            *(uint2*)&VsS[vd * 72 + g * 16 + vj * 4] = vreg[g];
        __syncthreads();

        // prefetch next tile AFTER the barrier: vmcnt drain lands at the
        // next iteration's first barrier, i.e. after the compute below.
        if (t0 + 64 < 1024) {
            const int tb = sbuf * 1024 + t0 + 64;
            kreg0 = *(const uint4*)(Kbase + (size_t)(tb + kr) * 512 + kc8 * 8);
            kreg1 = *(const uint4*)(Kbase + (size_t)(tb + kr + 32) * 512 + kc8 * 8);
            #pragma unroll
            for (int g = 0; g < 4; ++g)
                vreg[g] = *(const uint2*)(Vbase + (size_t)vd * 2048 + tb + g * 16 + vkq * 4);
        }

        // ---- S^T = K Q^T : lane holds 32 scores (log2 domain) of query l31
        f32x16 s0, s1;
        #pragma unroll
        for (int i = 0; i < 16; ++i) { s0[i] = 0.0f; s1[i] = 0.0f; }
        #pragma unroll
        for (int ks = 0; ks < 4; ++ks) {
            B8 k0, k1;
            k0.u = *(const uint4*)(&KsC[l31 * 72 + ks * 16 + half * 8]);
            k1.u = *(const uint4*)(&KsC[(32 + l31) * 72 + ks * 16 + half * 8]);
            s0 = __builtin_amdgcn_mfma_f32_32x32x16_bf16(k0.v, qf[ks], s0, 0, 0, 0);
            s1 = __builtin_amdgcn_mfma_f32_32x32x16_bf16(k1.v, qf[ks], s1, 0, 0, 0);
        }

        // ---- p = 2^s (bare v_exp_f32), accumulate l, pack P^T frags ----
        float ls = 0.0f;
        #pragma unroll
        for (int r = 0; r < 16; ++r) {
            s0[r] = __builtin_amdgcn_exp2f(s0[r]); ls += s0[r];
            s1[r] = __builtin_amdgcn_exp2f(s1[r]); ls += s1[r];
        }
        l_i += ls;

        B8 pf[4];
        #pragma unroll
        for (int j = 0; j < 8; ++j) {
            pf[0].e[j] = (bf16_t)s0[j];
            pf[1].e[j] = (bf16_t)s0[8 + j];
            pf[2].e[j] = (bf16_t)s1[j];
            pf[3].e[j] = (bf16_t)s1[8 + j];
        }

        // ---- O^T += V^T P^T ----
        #pragma unroll
        for (int c = 0; c < 4; ++c) {
            B8 va, vb;
            va.u = *(const uint4*)(&VsC[l31 * 72 + c * 16 + half * 8]);
            vb.u = *(const uint4*)(&VsC[(32 + l31) * 72 + c * 16 + half * 8]);
            o0 = __builtin_amdgcn_mfma_f32_32x32x16_bf16(va.v, pf[c].v, o0, 0, 0, 0);
            o1 = __builtin_amdgcn_mfma_f32_32x32x16_bf16(vb.v, pf[c].v, o1, 0, 0, 0);
        }
    }

    // ---- combine key-split partials via LDS, then normalize + store ----
    l_i += __shfl_xor(l_i, 32);
    __syncthreads();
    float* co = (float*)smraw;                 // [4][32*68]
    float* cl = co + 4 * 32 * 68;              // [4][64]
    if (ksplit == 1) {
        float* reg = co + qsub * (32 * 68);
        #pragma unroll
        for (int r = 0; r < 16; ++r) {
            reg[r * 68 + lane]        = o0[r];
            reg[(16 + r) * 68 + lane] = o1[r];
        }
        cl[qsub * 64 + lane] = l_i;
    }
    __syncthreads();
    if (ksplit == 0) {
        float* reg = co + qsub * (32 * 68);
        float inv = 1.0f / (l_i + cl[qsub * 64 + lane]);
        f16_t* Ob = O + ((size_t)(b * S_ + q0 + qsub * 32 + l31)) * 512 + h * 64;
        #pragma unroll
        for (int g = 0; g < 4; ++g) {
            H4 a, c;
            #pragma unroll
            for (int j = 0; j < 4; ++j) {
                int r = g * 4 + j;
                a.e[j] = (f16_t)((o0[r] + reg[r * 68 + lane]) * inv);
                c.e[j] = (f16_t)((o1[r] + reg[(16 + r) * 68 + lane]) * inv);
            }
            int d = 8 * g + 4 * half;
            *(uint2*)(Ob + d)      = a.u;
            *(uint2*)(Ob + 32 + d) = c.u;
        }
    }
}

// ---------------------------------------------------------------------------
// LDS-tiled output GEMM, post-barrier reg prefetch: 64x64x64, 4 waves
// (2x2 of 32x32). out = AO(f16) @ Wot^T + bo, fp32. grid (128, 8), 256 thr.
// ---------------------------------------------------------------------------
__global__ __launch_bounds__(256) void gemm_out_tiled(
    const f16_t* __restrict__ A, const f16_t* __restrict__ Wot,
    const float* __restrict__ bias, float* __restrict__ C)
{
    __shared__ f16_t As[64 * 72];
    __shared__ f16_t Bs[64 * 72];

    const int tid  = threadIdx.x;
    const int wave = tid >> 6, lane = tid & 63;
    const int l31  = lane & 31, half = lane >> 5;
    const int m0   = blockIdx.x * 64;
    const int n0   = blockIdx.y * 64;
    const int mw   = (wave & 1) * 32;
    const int nw   = (wave >> 1) * 32;

    const int sr  = tid >> 2;           // staging row 0..63
    const int so  = (tid & 3) * 16;     // staging col 0/16/32/48

    uint4 pA0, pA1, pB0, pB1;
    {
        const f16_t* ap = A   + (size_t)(m0 + sr) * 512 + so;
        const f16_t* bp = Wot + (size_t)(n0 + sr) * 512 + so;
        pA0 = *(const uint4*)(ap); pA1 = *(const uint4*)(ap + 8);
        pB0 = *(const uint4*)(bp); pB1 = *(const uint4*)(bp + 8);
    }

    f32x16 acc;
    #pragma unroll
    for (int i = 0; i < 16; ++i) acc[i] = 0.0f;

    for (int k0 = 0; k0 < 512; k0 += 64) {
        __syncthreads();
        *(uint4*)&As[sr * 72 + so]     = pA0;
        *(uint4*)&As[sr * 72 + so + 8] = pA1;
        *(uint4*)&Bs[sr * 72 + so]     = pB0;
        *(uint4*)&Bs[sr * 72 + so + 8] = pB1;
        __syncthreads();
        if (k0 + 64 < 512) {
            const f16_t* ap = A   + (size_t)(m0 + sr) * 512 + k0 + 64 + so;
            const f16_t* bp = Wot + (size_t)(n0 + sr) * 512 + k0 + 64 + so;
            pA0 = *(const uint4*)(ap); pA1 = *(const uint4*)(ap + 8);
            pB0 = *(const uint4*)(bp); pB1 = *(const uint4*)(bp + 8);
        }

        #pragma unroll
        for (int kc = 0; kc < 4; ++kc) {
            H8 a, b;
            a.u = *(const uint4*)&As[(mw + l31) * 72 + kc * 16 + half * 8];
            b.u = *(const uint4*)&Bs[(nw + l31) * 72 + kc * 16 + half * 8];
            acc = __builtin_amdgcn_mfma_f32_32x32x16_f16(a.v, b.v, acc, 0, 0, 0);
        }
    }

    const int n = n0 + nw + l31;
    const float bias0 = bias[n];
    #pragma unroll
    for (int r = 0; r < 16; ++r) {
        int m = m0 + mw + (r & 3) + 8 * (r >> 2) + 4 * half;
        C[(size_t)m * 512 + n] = acc[r] + bias0;
    }
}

// ---------------------------------------------------------------------------
extern "C" void kernel_launch(void* const* d_in, const int* in_sizes, int n_in,
                              void* d_out, int out_size, void* d_ws, size_t ws_size,
                              hipStream_t stream)
{
    const float* x_q = (const float*)d_in[0];
    const float* x_k = (const float*)d_in[1];
    const float* x_v = (const float*)d_in[2];
    const float* Wq  = (const float*)d_in[3];
    const float* bq  = (const float*)d_in[4];
    const float* Wk  = (const float*)d_in[5];
    const float* bk  = (const float*)d_in[6];
    const float* Wv  = (const float*)d_in[7];
    const float* bv  = (const float*)d_in[8];
    const float* Wo  = (const float*)d_in[9];
    const float* bo  = (const float*)d_in[10];
    float* out = (float*)d_out;

    // ws layout (~34 MB)
    char* W = (char*)d_ws;
    bf16_t* Wtq = (bf16_t*)W;                                    // 512 KB
    bf16_t* Wtk = Wtq + (size_t)8 * 64 * 512;
    bf16_t* Wtv = Wtk + (size_t)8 * 64 * 512;
    f16_t*  Wot = (f16_t*)(Wtv + (size_t)8 * 64 * 512);          // 512 KB
    bf16_t* Qb  = (bf16_t*)(Wot + (size_t)512 * 512);            // 8 MB
    bf16_t* Kb  = Qb + (size_t)M_ * 512;                         // 8 MB
    bf16_t* Vt  = Kb + (size_t)M_ * 512;                         // 8 MB
    f16_t*  AO  = (f16_t*)(Vt + (size_t)M_ * 512);               // 8 MB

    convert_weights<<<dim3(8, 8, 4), 256, 0, stream>>>(
        Wq, Wk, Wv, Wo, Wtq, Wtk, Wtv, Wot);

    proj_tiled<<<dim3(128, 4, 3), 256, 0, stream>>>(
        x_q, x_k, x_v, Wtq, Wtk, Wtv, bq, bk, bv, Qb, Kb, Vt);

    attn_mfma<<<dim3(S_ / 128, B_ * H_), 512, 0, stream>>>(Qb, Kb, Vt, AO);

    gemm_out_tiled<<<dim3(128, 8), 256, 0, stream>>>(AO, Wot, bo, out);
}

// Round 12
// 214.464 us; speedup vs baseline: 1.3731x; 1.0993x over previous
//
#include <hip/hip_runtime.h>

#define B_    4
#define S_    2048
#define H_    8
#define M_    (B_ * S_)   // 8192

typedef __bf16    bf16_t;
typedef _Float16  f16_t;
typedef __bf16   bf16x8 __attribute__((ext_vector_type(8)));
typedef __bf16   bf16x4 __attribute__((ext_vector_type(4)));
typedef _Float16 f16x8  __attribute__((ext_vector_type(8)));
typedef float    f32x16 __attribute__((ext_vector_type(16)));

union B8 { uint4 u; bf16x8 v; bf16_t e[8]; };
union B4 { uint2 u; bf16x4 v; bf16_t e[4]; };
union H8 { uint4 u; f16x8  v; f16_t  e[8]; };
union H4 { uint2 u; f16_t  e[4]; };

#define QSCALE 0.1803368801111204f   // 0.125 * log2(e): scores exit in log2 domain

// ---------------------------------------------------------------------------
// All weight converts in ONE launch. grid (8, 8, 4), 256 thr.
// z<3:  W[z] [8,512,64] fp32 -> Wt[z] [8,64,512] bf16 (y = head, x = k-tile)
// z==3: Wo [512,512] fp32 -> Wot [512n][512k] f16    (y = n-tile, x = k-tile)
// ---------------------------------------------------------------------------
__global__ __launch_bounds__(256) void convert_weights(
    const float* __restrict__ w0, const float* __restrict__ w1,
    const float* __restrict__ w2, const float* __restrict__ wo,
    bf16_t* __restrict__ t0, bf16_t* __restrict__ t1,
    bf16_t* __restrict__ t2, f16_t* __restrict__ wot)
{
    __shared__ float T[64][65];
    const int z   = blockIdx.z;
    const int k0  = blockIdx.x * 64;
    const int tid = threadIdx.x;
    const int row = tid & 63, q4 = tid >> 6;

    if (z < 3) {
        const float* W  = z == 0 ? w0 : z == 1 ? w1 : w2;
        bf16_t*      Wt = z == 0 ? t0 : z == 1 ? t1 : t2;
        const int h = blockIdx.y;
        const float* Wh = W + (size_t)h * 512 * 64;
        #pragma unroll
        for (int i = 0; i < 4; ++i) {
            int fq = q4 * 4 + i;
            float4 v = *(const float4*)(Wh + (size_t)(k0 + row) * 64 + fq * 4);
            T[row][fq * 4 + 0] = v.x; T[row][fq * 4 + 1] = v.y;
            T[row][fq * 4 + 2] = v.z; T[row][fq * 4 + 3] = v.w;
        }
        __syncthreads();
        bf16_t* Wth = Wt + (size_t)h * 64 * 512;
        #pragma unroll
        for (int i = 0; i < 4; ++i) {
            int kq = q4 * 4 + i;
            B4 o;
            #pragma unroll
            for (int j = 0; j < 4; ++j) o.e[j] = (bf16_t)T[kq * 4 + j][row];
            *(uint2*)(Wth + (size_t)row * 512 + k0 + kq * 4) = o.u;
        }
    } else {
        const int n0 = blockIdx.y * 64;
        #pragma unroll
        for (int i = 0; i < 4; ++i) {
            int fq = q4 * 4 + i;
            float4 v = *(const float4*)(wo + (size_t)(k0 + row) * 512 + n0 + fq * 4);
            T[row][fq * 4 + 0] = v.x; T[row][fq * 4 + 1] = v.y;
            T[row][fq * 4 + 2] = v.z; T[row][fq * 4 + 3] = v.w;
        }
        __syncthreads();
        #pragma unroll
        for (int i = 0; i < 4; ++i) {
            int kq = q4 * 4 + i;
            H4 o;
            #pragma unroll
            for (int j = 0; j < 4; ++j) o.e[j] = (f16_t)T[kq * 4 + j][row];
            *(uint2*)(wot + (size_t)(n0 + row) * 512 + k0 + kq * 4) = o.u;
        }
    }
}

// ---------------------------------------------------------------------------
// LDS-tiled QKV projection: 128M x 128N x BK=64 tile, 4 waves (2x2 of 64x64).
// grid (64, 4, 3) = 768 blocks (R9 geometry: 256-B output strips, WRITE 49MB).
// Prefetch issued AFTER the post-staging barrier (R11 fix): vmcnt drain lands
// at the next iteration's barrier, i.e. after the compute phase.
// z==0: Q -> concat bf16 scaled QSCALE; z==1: K; z==2: V -> Vt (transposed).
// C/D: col(n)=lane&31, row(m)=(r&3)+8*(r>>2)+4*half.
// ---------------------------------------------------------------------------
__global__ __launch_bounds__(256) void proj_tiled(
    const float* __restrict__ xq, const float* __restrict__ xk,
    const float* __restrict__ xv,
    const bf16_t* __restrict__ Wtq, const bf16_t* __restrict__ Wtk,
    const bf16_t* __restrict__ Wtv,
    const float* __restrict__ bq, const float* __restrict__ bk,
    const float* __restrict__ bv,
    bf16_t* __restrict__ Qb, bf16_t* __restrict__ Kb, bf16_t* __restrict__ Vt)
{
    __shared__ bf16_t As[128 * 72];
    __shared__ bf16_t Bs[128 * 72];

    const int z = blockIdx.z;
    const float*  X    = z == 0 ? xq  : z == 1 ? xk  : xv;
    const bf16_t* Wt   = z == 0 ? Wtq : z == 1 ? Wtk : Wtv;
    const float*  bias = z == 0 ? bq  : z == 1 ? bk  : bv;

    const int tid  = threadIdx.x;
    const int wave = tid >> 6, lane = tid & 63;
    const int l31  = lane & 31, half = lane >> 5;
    const int m0   = blockIdx.x * 128;
    const int n0   = blockIdx.y * 128;
    const int mw   = (wave & 1) * 64;
    const int nw   = (wave >> 1) * 64;

    const int sr = tid >> 1;            // staging row 0..127
    const int sc = (tid & 1) * 32;      // staging col-half 0/32

    float4 ra0[4], ra1[4];
    uint4  rb[4];
    {
        const float*  ap = X  + (size_t)(m0 + sr) * 512 + sc;
        const bf16_t* bp = Wt + (size_t)(n0 + sr) * 512 + sc;
        #pragma unroll
        for (int i = 0; i < 4; ++i) {
            ra0[i] = *(const float4*)(ap + i * 8);
            ra1[i] = *(const float4*)(ap + i * 8 + 4);
            rb[i]  = *(const uint4*)(bp + i * 8);
        }
    }

    f32x16 acc[2][2];
    #pragma unroll
    for (int mt = 0; mt < 2; ++mt)
        #pragma unroll
        for (int nt = 0; nt < 2; ++nt)
            #pragma unroll
            for (int i = 0; i < 16; ++i) acc[mt][nt][i] = 0.0f;

    for (int k0 = 0; k0 < 512; k0 += 64) {
        __syncthreads();
        #pragma unroll
        for (int i = 0; i < 4; ++i) {
            B8 w;
            w.e[0] = (bf16_t)ra0[i].x; w.e[1] = (bf16_t)ra0[i].y;
            w.e[2] = (bf16_t)ra0[i].z; w.e[3] = (bf16_t)ra0[i].w;
            w.e[4] = (bf16_t)ra1[i].x; w.e[5] = (bf16_t)ra1[i].y;
            w.e[6] = (bf16_t)ra1[i].z; w.e[7] = (bf16_t)ra1[i].w;
            *(uint4*)&As[sr * 72 + sc + i * 8] = w.u;
            *(uint4*)&Bs[sr * 72 + sc + i * 8] = rb[i];
        }
        __syncthreads();
        // prefetch AFTER the barrier: drain happens at next iter's barrier,
        // i.e. after the whole compute phase below.
        if (k0 + 64 < 512) {
            const float*  ap = X  + (size_t)(m0 + sr) * 512 + k0 + 64 + sc;
            const bf16_t* bp = Wt + (size_t)(n0 + sr) * 512 + k0 + 64 + sc;
            #pragma unroll
            for (int i = 0; i < 4; ++i) {
                ra0[i] = *(const float4*)(ap + i * 8);
                ra1[i] = *(const float4*)(ap + i * 8 + 4);
                rb[i]  = *(const uint4*)(bp + i * 8);
            }
        }

        #pragma unroll
        for (int kc = 0; kc < 4; ++kc) {
            B8 a0, a1, b0, b1;
            a0.u = *(const uint4*)&As[(mw + l31)      * 72 + kc * 16 + half * 8];
            a1.u = *(const uint4*)&As[(mw + 32 + l31) * 72 + kc * 16 + half * 8];
            b0.u = *(const uint4*)&Bs[(nw + l31)      * 72 + kc * 16 + half * 8];
            b1.u = *(const uint4*)&Bs[(nw + 32 + l31) * 72 + kc * 16 + half * 8];
            acc[0][0] = __builtin_amdgcn_mfma_f32_32x32x16_bf16(a0.v, b0.v, acc[0][0], 0, 0, 0);
            acc[0][1] = __builtin_amdgcn_mfma_f32_32x32x16_bf16(a0.v, b1.v, acc[0][1], 0, 0, 0);
            acc[1][0] = __builtin_amdgcn_mfma_f32_32x32x16_bf16(a1.v, b0.v, acc[1][0], 0, 0, 0);
            acc[1][1] = __builtin_amdgcn_mfma_f32_32x32x16_bf16(a1.v, b1.v, acc[1][1], 0, 0, 0);
        }
    }

    if (z <= 1) {
        const float sc_ = (z == 0) ? QSCALE : 1.0f;
        bf16_t* Out = (z == 0) ? Qb : Kb;
        #pragma unroll
        for (int mt = 0; mt < 2; ++mt)
            #pragma unroll
            for (int nt = 0; nt < 2; ++nt) {
                int n = n0 + nw + nt * 32 + l31;
                float bv_ = bias[n];
                #pragma unroll
                for (int r = 0; r < 16; ++r) {
                    int m = m0 + mw + mt * 32 + (r & 3) + 8 * (r >> 2) + 4 * half;
                    Out[(size_t)m * 512 + n] = (bf16_t)((acc[mt][nt][r] + bv_) * sc_);
                }
            }
    } else {
        const int b  = m0 >> 11;
        const int sb = (m0 & 2047);
        #pragma unroll
        for (int mt = 0; mt < 2; ++mt)
            #pragma unroll
            for (int nt = 0; nt < 2; ++nt) {
                int n = n0 + nw + nt * 32 + l31;
                float bv_ = bias[n];
                int h = n >> 6, d = n & 63;
                bf16_t* base = Vt + ((size_t)(b * 8 + h) * 64 + d) * 2048 + sb + mw + mt * 32;
                #pragma unroll
                for (int g = 0; g < 4; ++g) {
                    B4 p;
                    #pragma unroll
                    for (int j = 0; j < 4; ++j) p.e[j] = (bf16_t)(acc[mt][nt][g * 4 + j] + bv_);
                    *(uint2*)(base + 8 * g + 4 * half) = p.u;
                }
            }
    }
}

// ---------------------------------------------------------------------------
// MFMA flash attention (512 thr, in-block 2-way key split, post-barrier reg
// prefetch). Waves 0-3 keys [0,1024), waves 4-7 keys [1024,2048).
// Unnormalized partials combine linearly (no-max softmax, log2 domain) via
// one-time LDS exchange. Q-tile 128/block. grid (S/128, B*H) = 512 blocks.
// Q pre-scaled by 0.125*log2e in projection.
// ---------------------------------------------------------------------------
__global__ __launch_bounds__(512) void attn_mfma(
    const bf16_t* __restrict__ Q, const bf16_t* __restrict__ K,
    const bf16_t* __restrict__ Vt, f16_t* __restrict__ O)
{
    __shared__ char smraw[36864];
    bf16_t* KsBuf = (bf16_t*)smraw;            // [2][64*72]
    bf16_t* VsBuf = KsBuf + 2 * 64 * 72;       // [2][64*72]

    const int bh  = blockIdx.y;
    const int b   = bh >> 3, h = bh & 7;
    const int q0  = blockIdx.x * 128;
    const int tid = threadIdx.x;
    const int wave = tid >> 6, lane = tid & 63;
    const int l31 = lane & 31, half = lane >> 5;
    const int qsub = wave & 3, ksplit = wave >> 2;

    // Q fragments (B-operand: n=query=l31, k=d)
    bf16x8 qf[4];
    {
        const bf16_t* qp = Q + ((size_t)(b * S_ + q0 + qsub * 32 + l31)) * 512 + h * 64 + half * 8;
        #pragma unroll
        for (int ks = 0; ks < 4; ++ks) {
            B8 t; t.u = *(const uint4*)(qp + ks * 16);
            qf[ks] = t.v;
        }
    }

    f32x16 o0, o1;
    #pragma unroll
    for (int i = 0; i < 16; ++i) { o0[i] = 0.0f; o1[i] = 0.0f; }
    float l_i = 0.0f;

    const bf16_t* Kbase = K + ((size_t)b * S_) * 512 + h * 64;
    const bf16_t* Vbase = Vt + ((size_t)bh * 64) * 2048;

    // staging: threads 0-255 fill buffer 0 (keys 0-1023), 256-511 buffer 1
    const int sbuf = tid >> 8;
    const int p    = tid & 255;
    const int kr = p >> 3, kc8 = p & 7;
    const int vd = p >> 2, vj = p & 3;
    const int kqmap[4] = {0, 2, 1, 3};
    const int vkq = kqmap[vj];
    bf16_t* KsS = KsBuf + sbuf * (64 * 72);
    bf16_t* VsS = VsBuf + sbuf * (64 * 72);
    const bf16_t* KsC = KsBuf + ksplit * (64 * 72);
    const bf16_t* VsC = VsBuf + ksplit * (64 * 72);

    // register staging (prefetch): 2 uint4 K + 4 uint2 V per thread
    uint4 kreg0, kreg1;
    uint2 vreg[4];
    {
        const int tb = sbuf * 1024;
        kreg0 = *(const uint4*)(Kbase + (size_t)(tb + kr) * 512 + kc8 * 8);
        kreg1 = *(const uint4*)(Kbase + (size_t)(tb + kr + 32) * 512 + kc8 * 8);
        #pragma unroll
        for (int g = 0; g < 4; ++g)
            vreg[g] = *(const uint2*)(Vbase + (size_t)vd * 2048 + tb + g * 16 + vkq * 4);
    }

    for (int t0 = 0; t0 < 1024; t0 += 64) {
        __syncthreads();
        *(uint4*)&KsS[kr * 72 + kc8 * 8]        = kreg0;
        *(uint4*)&KsS[(kr + 32) * 72 + kc8 * 8] = kreg1;
        #pragma unroll
        for (int g = 0; g < 4; ++g)
            *(uint2*)&VsS[vd * 72 + g * 16 + vj * 4] = vreg[g];
        __syncthreads();

        // prefetch next tile AFTER the barrier: vmcnt drain lands at the
        // next iteration's first barrier, i.e. after the compute below.
        if (t0 + 64 < 1024) {
            const int tb = sbuf * 1024 + t0 + 64;
            kreg0 = *(const uint4*)(Kbase + (size_t)(tb + kr) * 512 + kc8 * 8);
            kreg1 = *(const uint4*)(Kbase + (size_t)(tb + kr + 32) * 512 + kc8 * 8);
            #pragma unroll
            for (int g = 0; g < 4; ++g)
                vreg[g] = *(const uint2*)(Vbase + (size_t)vd * 2048 + tb + g * 16 + vkq * 4);
        }

        // ---- S^T = K Q^T : lane holds 32 scores (log2 domain) of query l31
        f32x16 s0, s1;
        #pragma unroll
        for (int i = 0; i < 16; ++i) { s0[i] = 0.0f; s1[i] = 0.0f; }
        #pragma unroll
        for (int ks = 0; ks < 4; ++ks) {
            B8 k0, k1;
            k0.u = *(const uint4*)(&KsC[l31 * 72 + ks * 16 + half * 8]);
            k1.u = *(const uint4*)(&KsC[(32 + l31) * 72 + ks * 16 + half * 8]);
            s0 = __builtin_amdgcn_mfma_f32_32x32x16_bf16(k0.v, qf[ks], s0, 0, 0, 0);
            s1 = __builtin_amdgcn_mfma_f32_32x32x16_bf16(k1.v, qf[ks], s1, 0, 0, 0);
        }

        // ---- p = 2^s (bare v_exp_f32), accumulate l, pack P^T frags ----
        float ls = 0.0f;
        #pragma unroll
        for (int r = 0; r < 16; ++r) {
            s0[r] = __builtin_amdgcn_exp2f(s0[r]); ls += s0[r];
            s1[r] = __builtin_amdgcn_exp2f(s1[r]); ls += s1[r];
        }
        l_i += ls;

        B8 pf[4];
        #pragma unroll
        for (int j = 0; j < 8; ++j) {
            pf[0].e[j] = (bf16_t)s0[j];
            pf[1].e[j] = (bf16_t)s0[8 + j];
            pf[2].e[j] = (bf16_t)s1[j];
            pf[3].e[j] = (bf16_t)s1[8 + j];
        }

        // ---- O^T += V^T P^T ----
        #pragma unroll
        for (int c = 0; c < 4; ++c) {
            B8 va, vb;
            va.u = *(const uint4*)(&VsC[l31 * 72 + c * 16 + half * 8]);
            vb.u = *(const uint4*)(&VsC[(32 + l31) * 72 + c * 16 + half * 8]);
            o0 = __builtin_amdgcn_mfma_f32_32x32x16_bf16(va.v, pf[c].v, o0, 0, 0, 0);
            o1 = __builtin_amdgcn_mfma_f32_32x32x16_bf16(vb.v, pf[c].v, o1, 0, 0, 0);
        }
    }

    // ---- combine key-split partials via LDS, then normalize + store ----
    l_i += __shfl_xor(l_i, 32);
    __syncthreads();
    float* co = (float*)smraw;                 // [4][32*68]
    float* cl = co + 4 * 32 * 68;              // [4][64]
    if (ksplit == 1) {
        float* reg = co + qsub * (32 * 68);
        #pragma unroll
        for (int r = 0; r < 16; ++r) {
            reg[r * 68 + lane]        = o0[r];
            reg[(16 + r) * 68 + lane] = o1[r];
        }
        cl[qsub * 64 + lane] = l_i;
    }
    __syncthreads();
    if (ksplit == 0) {
        float* reg = co + qsub * (32 * 68);
        float inv = 1.0f / (l_i + cl[qsub * 64 + lane]);
        f16_t* Ob = O + ((size_t)(b * S_ + q0 + qsub * 32 + l31)) * 512 + h * 64;
        #pragma unroll
        for (int g = 0; g < 4; ++g) {
            H4 a, c;
            #pragma unroll
            for (int j = 0; j < 4; ++j) {
                int r = g * 4 + j;
                a.e[j] = (f16_t)((o0[r] + reg[r * 68 + lane]) * inv);
                c.e[j] = (f16_t)((o1[r] + reg[(16 + r) * 68 + lane]) * inv);
            }
            int d = 8 * g + 4 * half;
            *(uint2*)(Ob + d)      = a.u;
            *(uint2*)(Ob + 32 + d) = c.u;
        }
    }
}

// ---------------------------------------------------------------------------
// LDS-tiled output GEMM, post-barrier reg prefetch: 64x64x64, 4 waves
// (2x2 of 32x32). out = AO(f16) @ Wot^T + bo, fp32. grid (128, 8), 256 thr.
// ---------------------------------------------------------------------------
__global__ __launch_bounds__(256) void gemm_out_tiled(
    const f16_t* __restrict__ A, const f16_t* __restrict__ Wot,
    const float* __restrict__ bias, float* __restrict__ C)
{
    __shared__ f16_t As[64 * 72];
    __shared__ f16_t Bs[64 * 72];

    const int tid  = threadIdx.x;
    const int wave = tid >> 6, lane = tid & 63;
    const int l31  = lane & 31, half = lane >> 5;
    const int m0   = blockIdx.x * 64;
    const int n0   = blockIdx.y * 64;
    const int mw   = (wave & 1) * 32;
    const int nw   = (wave >> 1) * 32;

    const int sr  = tid >> 2;           // staging row 0..63
    const int so  = (tid & 3) * 16;     // staging col 0/16/32/48

    uint4 pA0, pA1, pB0, pB1;
    {
        const f16_t* ap = A   + (size_t)(m0 + sr) * 512 + so;
        const f16_t* bp = Wot + (size_t)(n0 + sr) * 512 + so;
        pA0 = *(const uint4*)(ap); pA1 = *(const uint4*)(ap + 8);
        pB0 = *(const uint4*)(bp); pB1 = *(const uint4*)(bp + 8);
    }

    f32x16 acc;
    #pragma unroll
    for (int i = 0; i < 16; ++i) acc[i] = 0.0f;

    for (int k0 = 0; k0 < 512; k0 += 64) {
        __syncthreads();
        *(uint4*)&As[sr * 72 + so]     = pA0;
        *(uint4*)&As[sr * 72 + so + 8] = pA1;
        *(uint4*)&Bs[sr * 72 + so]     = pB0;
        *(uint4*)&Bs[sr * 72 + so + 8] = pB1;
        __syncthreads();
        if (k0 + 64 < 512) {
            const f16_t* ap = A   + (size_t)(m0 + sr) * 512 + k0 + 64 + so;
            const f16_t* bp = Wot + (size_t)(n0 + sr) * 512 + k0 + 64 + so;
            pA0 = *(const uint4*)(ap); pA1 = *(const uint4*)(ap + 8);
            pB0 = *(const uint4*)(bp); pB1 = *(const uint4*)(bp + 8);
        }

        #pragma unroll
        for (int kc = 0; kc < 4; ++kc) {
            H8 a, b;
            a.u = *(const uint4*)&As[(mw + l31) * 72 + kc * 16 + half * 8];
            b.u = *(const uint4*)&Bs[(nw + l31) * 72 + kc * 16 + half * 8];
            acc = __builtin_amdgcn_mfma_f32_32x32x16_f16(a.v, b.v, acc, 0, 0, 0);
        }
    }

    const int n = n0 + nw + l31;
    const float bias0 = bias[n];
    #pragma unroll
    for (int r = 0; r < 16; ++r) {
        int m = m0 + mw + (r & 3) + 8 * (r >> 2) + 4 * half;
        C[(size_t)m * 512 + n] = acc[r] + bias0;
    }
}

// ---------------------------------------------------------------------------
extern "C" void kernel_launch(void* const* d_in, const int* in_sizes, int n_in,
                              void* d_out, int out_size, void* d_ws, size_t ws_size,
                              hipStream_t stream)
{
    const float* x_q = (const float*)d_in[0];
    const float* x_k = (const float*)d_in[1];
    const float* x_v = (const float*)d_in[2];
    const float* Wq  = (const float*)d_in[3];
    const float* bq  = (const float*)d_in[4];
    const float* Wk  = (const float*)d_in[5];
    const float* bk  = (const float*)d_in[6];
    const float* Wv  = (const float*)d_in[7];
    const float* bv  = (const float*)d_in[8];
    const float* Wo  = (const float*)d_in[9];
    const float* bo  = (const float*)d_in[10];
    float* out = (float*)d_out;

    // ws layout (~34 MB)
    char* W = (char*)d_ws;
    bf16_t* Wtq = (bf16_t*)W;                                    // 512 KB
    bf16_t* Wtk = Wtq + (size_t)8 * 64 * 512;
    bf16_t* Wtv = Wtk + (size_t)8 * 64 * 512;
    f16_t*  Wot = (f16_t*)(Wtv + (size_t)8 * 64 * 512);          // 512 KB
    bf16_t* Qb  = (bf16_t*)(Wot + (size_t)512 * 512);            // 8 MB
    bf16_t* Kb  = Qb + (size_t)M_ * 512;                         // 8 MB
    bf16_t* Vt  = Kb + (size_t)M_ * 512;                         // 8 MB
    f16_t*  AO  = (f16_t*)(Vt + (size_t)M_ * 512);               // 8 MB

    convert_weights<<<dim3(8, 8, 4), 256, 0, stream>>>(
        Wq, Wk, Wv, Wo, Wtq, Wtk, Wtv, Wot);

    proj_tiled<<<dim3(64, 4, 3), 256, 0, stream>>>(
        x_q, x_k, x_v, Wtq, Wtk, Wtv, bq, bk, bv, Qb, Kb, Vt);

    attn_mfma<<<dim3(S_ / 128, B_ * H_), 512, 0, stream>>>(Qb, Kb, Vt, AO);

    gemm_out_tiled<<<dim3(128, 8), 256, 0, stream>>>(AO, Wot, bo, out);
}